// Round 8
// baseline (598.379 us; speedup 1.0000x reference)
//
#include <hip/hip_runtime.h>
#include <hip/hip_bf16.h>

#define FDIM 128
#define BROWS 32     // i1 rows per bucket: bin = i1>>5, loc = i1&31
#define NBLK 256     // hist/scatter partition blocks (= D2 grid)

// ---- bf16 helpers (manual, RNE) ----
static __device__ __forceinline__ unsigned short f2bf(float x) {
    unsigned u = __float_as_uint(x);
    unsigned r = 0x7fffu + ((u >> 16) & 1u);
    return (unsigned short)((u + r) >> 16);
}
static __device__ __forceinline__ float bf_lo(unsigned u) { return __uint_as_float(u << 16); }
static __device__ __forceinline__ float bf_hi(unsigned u) { return __uint_as_float(u & 0xffff0000u); }

// ---- device-scope grid barrier (persistent grid, all blocks co-resident) ----
static __device__ __forceinline__ void gbar(unsigned* cnt, unsigned* gen, unsigned nblk) {
    __syncthreads();
    if (threadIdx.x == 0) {
        unsigned g = __hip_atomic_load(gen, __ATOMIC_RELAXED, __HIP_MEMORY_SCOPE_AGENT);
        __threadfence();   // release: wbl2
        if (__hip_atomic_fetch_add(cnt, 1u, __ATOMIC_ACQ_REL, __HIP_MEMORY_SCOPE_AGENT) == nblk - 1) {
            __hip_atomic_store(cnt, 0u, __ATOMIC_RELAXED, __HIP_MEMORY_SCOPE_AGENT);
            __hip_atomic_fetch_add(gen, 1u, __ATOMIC_ACQ_REL, __HIP_MEMORY_SCOPE_AGENT);
        } else {
            while (__hip_atomic_load(gen, __ATOMIC_ACQUIRE, __HIP_MEMORY_SCOPE_AGENT) == g)
                __builtin_amdgcn_s_sleep(1);
        }
        __threadfence();   // acquire side: inv
    }
    __syncthreads();
}

// ---- D1: gemm (Ws built in-block) + fused histogram + counter init.
// Blocks [0,gemmBlocks): G = F @ (W+W^T) in bf16.
// Blocks [gemmBlocks, gemmBlocks+NBLK): LDS histogram -> M[b][k] (strided dump).
__global__ __launch_bounds__(256, 2) void k_gemm_hist(
    const float* __restrict__ Fm, const float* __restrict__ W,
    const int* __restrict__ idx, unsigned short* __restrict__ Gbf,
    unsigned* __restrict__ M, unsigned* __restrict__ ctr,
    int N, int E, int nb, int gemmBlocks) {
    __shared__ float sWs[FDIM * FDIM];   // 64 KB (hist blocks reuse as counters)
    __shared__ float sF[32][FDIM];       // 16 KB

    int bid = blockIdx.x;
    if (bid >= gemmBlocks) {
        // ---- hist path ----
        int hb = bid - gemmBlocks;
        unsigned* cnt = (unsigned*)sWs;
        if (hb == 0 && threadIdx.x < 8) ctr[threadIdx.x] = 0u;
        for (int i = threadIdx.x; i < nb; i += 256) cnt[i] = 0;
        __syncthreads();
        int chunk = (E + NBLK - 1) / NBLK;
        int s = hb * chunk;
        int e_end = min(E, s + chunk);
        for (int e = s + threadIdx.x; e < e_end; e += 256) {
            int i1 = idx[E + e];
            atomicAdd(&cnt[i1 >> 5], 1u);
        }
        __syncthreads();
        for (int i = threadIdx.x; i < nb; i += 256)
            M[(size_t)i * NBLK + hb] = cnt[i];
        return;
    }

    // ---- gemm path ----
    for (int k = threadIdx.x; k < 4096; k += 256) {   // 16384 elems / 4
        int i = k >> 5, c4 = (k & 31) * 4;
        float4 a = *(const float4*)(W + i * FDIM + c4);
        a.x += W[(c4 + 0) * FDIM + i];
        a.y += W[(c4 + 1) * FDIM + i];
        a.z += W[(c4 + 2) * FDIM + i];
        a.w += W[(c4 + 3) * FDIM + i];
        *(float4*)(sWs + i * FDIM + c4) = a;
    }
    int row0 = bid * 32;
    for (int k = threadIdx.x; k < 32 * FDIM / 4; k += 256) {
        int r = k >> 5, c = k & 31;
        int gr = row0 + r;
        float4 v = make_float4(0.f, 0.f, 0.f, 0.f);
        if (gr < N) v = ((const float4*)Fm)[(size_t)gr * (FDIM / 4) + c];
        ((float4*)&sF[r][0])[c] = v;
    }
    __syncthreads();

    int tx = threadIdx.x & 31;
    int ty = threadIdx.x >> 5;
    int c0 = tx * 4;
    float acc[4][4] = {};
    for (int i = 0; i < FDIM; ++i) {
        float4 w = *(const float4*)&sWs[i * FDIM + c0];
        float f0 = sF[ty * 4 + 0][i];
        float f1 = sF[ty * 4 + 1][i];
        float f2 = sF[ty * 4 + 2][i];
        float f3 = sF[ty * 4 + 3][i];
        acc[0][0] = fmaf(f0, w.x, acc[0][0]); acc[0][1] = fmaf(f0, w.y, acc[0][1]);
        acc[0][2] = fmaf(f0, w.z, acc[0][2]); acc[0][3] = fmaf(f0, w.w, acc[0][3]);
        acc[1][0] = fmaf(f1, w.x, acc[1][0]); acc[1][1] = fmaf(f1, w.y, acc[1][1]);
        acc[1][2] = fmaf(f1, w.z, acc[1][2]); acc[1][3] = fmaf(f1, w.w, acc[1][3]);
        acc[2][0] = fmaf(f2, w.x, acc[2][0]); acc[2][1] = fmaf(f2, w.y, acc[2][1]);
        acc[2][2] = fmaf(f2, w.z, acc[2][2]); acc[2][3] = fmaf(f2, w.w, acc[2][3]);
        acc[3][0] = fmaf(f3, w.x, acc[3][0]); acc[3][1] = fmaf(f3, w.y, acc[3][1]);
        acc[3][2] = fmaf(f3, w.z, acc[3][2]); acc[3][3] = fmaf(f3, w.w, acc[3][3]);
    }
    for (int r = 0; r < 4; ++r) {
        int gr = row0 + ty * 4 + r;
        if (gr < N) {
            ushort4 o;
            o.x = f2bf(acc[r][0]); o.y = f2bf(acc[r][1]);
            o.z = f2bf(acc[r][2]); o.w = f2bf(acc[r][3]);
            *(ushort4*)(Gbf + (size_t)gr * FDIM + c0) = o;
        }
    }
}

// ---- D2: persistent sort kernel. 256 blocks x 512 threads, 3 grid barriers.
// B: wave-per-bucket totals; C: block0 scan -> bucketStart; D: wave-per-bucket
// cursor prefix (M[b][k] -> start positions); E: LDS-cursor scatter. ----
__global__ __launch_bounds__(512) void k_sort(
    const int* __restrict__ idx, const int* __restrict__ mol, int E, int nb,
    unsigned* __restrict__ M, unsigned* __restrict__ tot,
    unsigned* __restrict__ bucketStart, unsigned* __restrict__ sortedE,
    unsigned* __restrict__ ctr) {
    extern __shared__ unsigned sh[];
    __shared__ unsigned wsum8[8];
    unsigned* barCnt = ctr + 0;
    unsigned* barGen = ctr + 1;
    const int tid = threadIdx.x, bid = blockIdx.x;
    const int lane = tid & 63, wid = tid >> 6;
    const int b = bid * 8 + wid;

    // Phase B: tot[b] = sum_k M[b][k]
    unsigned v0 = 0, v1 = 0, v2 = 0, v3 = 0;
    if (b < nb) {
        uint4 m4 = *(const uint4*)(M + (size_t)b * NBLK + lane * 4);
        v0 = m4.x; v1 = m4.y; v2 = m4.z; v3 = m4.w;
        unsigned t = v0 + v1 + v2 + v3;
        for (int d = 1; d < 64; d <<= 1) t += __shfl_xor(t, d, 64);
        if (lane == 0) tot[b] = t;
    }
    gbar(barCnt, barGen, gridDim.x);

    // Phase C: block 0 exclusive-scans tot -> bucketStart
    if (bid == 0) {
        unsigned a0 = (4 * tid + 0 < nb) ? tot[4 * tid + 0] : 0u;
        unsigned a1 = (4 * tid + 1 < nb) ? tot[4 * tid + 1] : 0u;
        unsigned a2 = (4 * tid + 2 < nb) ? tot[4 * tid + 2] : 0u;
        unsigned a3 = (4 * tid + 3 < nb) ? tot[4 * tid + 3] : 0u;
        unsigned l0 = 0, l1 = a0, l2 = a0 + a1, l3 = a0 + a1 + a2;
        unsigned s = l3 + a3;
        unsigned incl = s;
        for (int d = 1; d < 64; d <<= 1) {
            unsigned u = __shfl_up(incl, d, 64);
            if (lane >= d) incl += u;
        }
        if (lane == 63) wsum8[wid] = incl;
        __syncthreads();
        unsigned woff = 0;
        for (int i = 0; i < wid; ++i) woff += wsum8[i];
        unsigned base = woff + incl - s;
        if (4 * tid + 0 < nb) bucketStart[4 * tid + 0] = base + l0;
        if (4 * tid + 1 < nb) bucketStart[4 * tid + 1] = base + l1;
        if (4 * tid + 2 < nb) bucketStart[4 * tid + 2] = base + l2;
        if (4 * tid + 3 < nb) bucketStart[4 * tid + 3] = base + l3;
        if (tid == 0) {
            unsigned total = 0;
            for (int i = 0; i < 8; ++i) total += wsum8[i];
            bucketStart[nb] = total;
        }
    }
    gbar(barCnt, barGen, gridDim.x);

    // Phase D: per-bucket exclusive prefix over k -> cursor starts in M
    if (b < nb) {
        unsigned bs = bucketStart[b];
        unsigned p0 = 0, p1 = v0, p2 = v0 + v1, p3 = v0 + v1 + v2;
        unsigned s = p3 + v3;
        unsigned incl = s;
        for (int d = 1; d < 64; d <<= 1) {
            unsigned u = __shfl_up(incl, d, 64);
            if (lane >= d) incl += u;
        }
        unsigned base = bs + incl - s;
        uint4 w4;
        w4.x = base + p0; w4.y = base + p1; w4.z = base + p2; w4.w = base + p3;
        *(uint4*)(M + (size_t)b * NBLK + lane * 4) = w4;
    }
    gbar(barCnt, barGen, gridDim.x);

    // Phase E: scatter via LDS cursors; this block is partition k = bid
    unsigned* cur = sh;
    for (int i = tid; i < nb; i += 512)
        cur[i] = M[(size_t)i * NBLK + bid];
    __syncthreads();
    int chunk = (E + NBLK - 1) / NBLK;
    int s0 = bid * chunk;
    int e_end = min(E, s0 + chunk);
    for (int e = s0 + tid; e < e_end; e += 512) {
        int i0 = idx[e];
        int i1 = idx[E + e];
        int m  = mol[e];
        int bb = i1 >> 5;
        int loc = i1 & 31;
        unsigned pos = atomicAdd(&cur[bb], 1u);
        sortedE[pos] = (unsigned)i0 | ((unsigned)m << 16) | ((unsigned)loc << 26);
    }
}

// ---- D3: edge kernel (BROWS=32, ILP-2) + last-8-blocks reduction ----
__global__ __launch_bounds__(256) void edge_kernel(
    const unsigned short* __restrict__ Gbf, const float* __restrict__ Fm,
    const unsigned* __restrict__ sortedE, const unsigned* __restrict__ bucketStart,
    float* __restrict__ part, float* __restrict__ out,
    unsigned* __restrict__ done, int N, int nb, int Mout) {
    __shared__ unsigned short sFrow[BROWS * FDIM];   // 8 KB
    __shared__ float smol[1024];                     // 4 KB
    __shared__ unsigned sOld;

    const int tid = threadIdx.x;
    int b = blockIdx.x;
    int row0 = b * BROWS;
    int nrow = min(BROWS, N - row0);
    for (int k = tid; k < nrow * (FDIM / 4); k += 256) {
        int r = k >> 5, c = k & 31;
        float4 v = ((const float4*)(Fm + (size_t)(row0 + r) * FDIM))[c];
        ushort4 o;
        o.x = f2bf(v.x); o.y = f2bf(v.y); o.z = f2bf(v.z); o.w = f2bf(v.w);
        *(ushort4*)(sFrow + r * FDIM + c * 4) = o;
    }
    for (int i = tid; i < 1024; i += 256) smol[i] = 0.f;
    __syncthreads();

    const int s = bucketStart[b];
    const int e_end = bucketStart[b + 1];
    const int lane = tid & 63;
    const int sub  = lane >> 4;
    const int t16  = lane & 15;
    const int off16 = t16 * 8;
    const int wid  = tid >> 6;

    for (int base = s + wid * 8; base < e_end; base += 32) {
        int e0 = base + sub;
        int e1 = base + 4 + sub;
        bool va = (e0 < e_end), vb = (e1 < e_end);
        unsigned pk0 = va ? sortedE[e0] : 0u;
        unsigned pk1 = vb ? sortedE[e1] : 0u;
        const uint4 g0 = *(const uint4*)(Gbf + (size_t)(pk0 & 0xffff) * FDIM + off16);
        const uint4 g1 = *(const uint4*)(Gbf + (size_t)(pk1 & 0xffff) * FDIM + off16);
        const uint4 f0 = *(const uint4*)(sFrow + ((pk0 >> 26) << 7) + off16);
        const uint4 f1 = *(const uint4*)(sFrow + ((pk1 >> 26) << 7) + off16);
        float p0, p1;
        p0 = bf_lo(g0.x) * bf_lo(f0.x);
        p0 = fmaf(bf_hi(g0.x), bf_hi(f0.x), p0);
        p0 = fmaf(bf_lo(g0.y), bf_lo(f0.y), p0);
        p0 = fmaf(bf_hi(g0.y), bf_hi(f0.y), p0);
        p0 = fmaf(bf_lo(g0.z), bf_lo(f0.z), p0);
        p0 = fmaf(bf_hi(g0.z), bf_hi(f0.z), p0);
        p0 = fmaf(bf_lo(g0.w), bf_lo(f0.w), p0);
        p0 = fmaf(bf_hi(g0.w), bf_hi(f0.w), p0);
        p1 = bf_lo(g1.x) * bf_lo(f1.x);
        p1 = fmaf(bf_hi(g1.x), bf_hi(f1.x), p1);
        p1 = fmaf(bf_lo(g1.y), bf_lo(f1.y), p1);
        p1 = fmaf(bf_hi(g1.y), bf_hi(f1.y), p1);
        p1 = fmaf(bf_lo(g1.z), bf_lo(f1.z), p1);
        p1 = fmaf(bf_hi(g1.z), bf_hi(f1.z), p1);
        p1 = fmaf(bf_lo(g1.w), bf_lo(f1.w), p1);
        p1 = fmaf(bf_hi(g1.w), bf_hi(f1.w), p1);
        p0 += __shfl_xor(p0, 1, 16);
        p0 += __shfl_xor(p0, 2, 16);
        p0 += __shfl_xor(p0, 4, 16);
        p0 += __shfl_xor(p0, 8, 16);
        p1 += __shfl_xor(p1, 1, 16);
        p1 += __shfl_xor(p1, 2, 16);
        p1 += __shfl_xor(p1, 4, 16);
        p1 += __shfl_xor(p1, 8, 16);
        if (t16 == 0 && va) atomicAdd(&smol[(pk0 >> 16) & 0x3ff], p0);
        if (t16 == 0 && vb) atomicAdd(&smol[(pk1 >> 16) & 0x3ff], p1);
    }
    __syncthreads();
    float* prow = part + (size_t)b * 1024;
    for (int i = tid; i < 1024; i += 256) prow[i] = smol[i];
    __syncthreads();
    if (tid == 0) {
        __threadfence();   // release: push part row past XCD L2
        sOld = __hip_atomic_fetch_add(done, 1u, __ATOMIC_ACQ_REL, __HIP_MEMORY_SCOPE_AGENT);
    }
    __syncthreads();
    unsigned old = sOld;

    if ((int)old >= nb - 8) {
        // one of the last 8 blocks: reduce a 128-molecule slice
        if (tid == 0) {
            while (__hip_atomic_load(done, __ATOMIC_ACQUIRE, __HIP_MEMORY_SCOPE_AGENT) < (unsigned)nb)
                __builtin_amdgcn_s_sleep(8);
        }
        __syncthreads();
        __threadfence();   // acquire side: inv caches
        int r = (int)old - (nb - 8);             // 0..7
        int m = r * 128 + (tid & 127);
        int half = tid >> 7;                     // 0 or 1
        float ssum = 0.f;
        for (int bb = half; bb < nb; bb += 2)
            ssum += part[(size_t)bb * 1024 + m];
        __syncthreads();                         // smol reuse
        smol[tid] = ssum;
        __syncthreads();
        if (tid < 128 && m < Mout)
            out[m] = smol[tid] + smol[tid + 128];
    }
}

extern "C" void kernel_launch(void* const* d_in, const int* in_sizes, int n_in,
                              void* d_out, int out_size, void* d_ws, size_t ws_size,
                              hipStream_t stream) {
    const float* Fm = (const float*)d_in[0];
    const float* W  = (const float*)d_in[1];
    const int* idx  = (const int*)d_in[2];
    const int* mol  = (const int*)d_in[3];
    float* out = (float*)d_out;

    const int N = in_sizes[0] / FDIM;   // 50000
    const int E = in_sizes[3];          // 1600000
    const int nb = (N + BROWS - 1) / BROWS;   // 1563
    const int gemmBlocks = (N + 31) / 32;     // 1563

    // workspace layout (~27 MB)
    char* ws = (char*)d_ws;
    size_t o = 0;
    unsigned short* Gbf = (unsigned short*)(ws + o); o += ((size_t)N * FDIM * 2 + 255) & ~(size_t)255;
    unsigned* sortedE = (unsigned*)(ws + o);         o += ((size_t)E * 4 + 255) & ~(size_t)255;
    unsigned* M = (unsigned*)(ws + o);               o += ((size_t)nb * NBLK * 4 + 255) & ~(size_t)255;
    unsigned* tot = (unsigned*)(ws + o);             o += ((size_t)nb * 4 + 255) & ~(size_t)255;
    unsigned* bucketStart = (unsigned*)(ws + o);     o += ((size_t)(nb + 1) * 4 + 255) & ~(size_t)255;
    float* part = (float*)(ws + o);                  o += (size_t)nb * 1024 * sizeof(float);
    unsigned* ctr = (unsigned*)(ws + o);             o += 256;   // [0]=barCnt [1]=barGen [2]=done

    k_gemm_hist<<<gemmBlocks + NBLK, 256, 0, stream>>>(
        Fm, W, idx, Gbf, M, ctr, N, E, nb, gemmBlocks);

    k_sort<<<NBLK, 512, (size_t)nb * 4, stream>>>(
        idx, mol, E, nb, M, tot, bucketStart, sortedE, ctr);

    edge_kernel<<<nb, 256, 0, stream>>>(
        Gbf, Fm, sortedE, bucketStart, part, out, ctr + 2, N, nb, out_size);
}

// Round 9
// 392.361 us; speedup vs baseline: 1.5251x; 1.5251x over previous
//
#include <hip/hip_runtime.h>
#include <hip/hip_bf16.h>

#define FDIM 128
#define BROWS 32     // i1 rows per bucket: bin = i1>>5, loc = i1&31
#define NBLK 64      // hist/scatter partitions: runs of ~16 = one 64B line per block

// ---- bf16 helpers (manual, RNE) ----
static __device__ __forceinline__ unsigned short f2bf(float x) {
    unsigned u = __float_as_uint(x);
    unsigned r = 0x7fffu + ((u >> 16) & 1u);
    return (unsigned short)((u + r) >> 16);
}
static __device__ __forceinline__ float bf_lo(unsigned u) { return __uint_as_float(u << 16); }
static __device__ __forceinline__ float bf_hi(unsigned u) { return __uint_as_float(u & 0xffff0000u); }

// ---- k1: gemm (Ws built in-block from W+W^T) + fused histogram.
// Blocks [0,gemmBlocks): G = F @ (W+W^T) in bf16.
// Blocks [gemmBlocks, gemmBlocks+NBLK): LDS histogram -> M[k][b] (coalesced dump).
__global__ __launch_bounds__(256, 2) void k_gemm_hist(
    const float* __restrict__ Fm, const float* __restrict__ W,
    const int* __restrict__ idx, unsigned short* __restrict__ Gbf,
    unsigned* __restrict__ M, int N, int E, int nb, int gemmBlocks) {
    __shared__ float sWs[FDIM * FDIM];   // 64 KB (hist blocks reuse as counters)
    __shared__ float sF[32][FDIM];       // 16 KB

    int bid = blockIdx.x;
    if (bid >= gemmBlocks) {
        // ---- hist path ----
        int hb = bid - gemmBlocks;
        unsigned* cnt = (unsigned*)sWs;
        for (int i = threadIdx.x; i < nb; i += 256) cnt[i] = 0;
        __syncthreads();
        int chunk = (E + NBLK - 1) / NBLK;
        int s = hb * chunk;
        int e_end = min(E, s + chunk);
        for (int e = s + threadIdx.x; e < e_end; e += 256) {
            int i1 = idx[E + e];
            atomicAdd(&cnt[i1 >> 5], 1u);
        }
        __syncthreads();
        for (int i = threadIdx.x; i < nb; i += 256)
            M[(size_t)hb * nb + i] = cnt[i];
        return;
    }

    // ---- gemm path ----
    for (int k = threadIdx.x; k < 4096; k += 256) {   // 16384 elems / 4
        int i = k >> 5, c4 = (k & 31) * 4;
        float4 a = *(const float4*)(W + i * FDIM + c4);
        a.x += W[(c4 + 0) * FDIM + i];
        a.y += W[(c4 + 1) * FDIM + i];
        a.z += W[(c4 + 2) * FDIM + i];
        a.w += W[(c4 + 3) * FDIM + i];
        *(float4*)(sWs + i * FDIM + c4) = a;
    }
    int row0 = bid * 32;
    for (int k = threadIdx.x; k < 32 * FDIM / 4; k += 256) {
        int r = k >> 5, c = k & 31;
        int gr = row0 + r;
        float4 v = make_float4(0.f, 0.f, 0.f, 0.f);
        if (gr < N) v = ((const float4*)Fm)[(size_t)gr * (FDIM / 4) + c];
        ((float4*)&sF[r][0])[c] = v;
    }
    __syncthreads();

    int tx = threadIdx.x & 31;
    int ty = threadIdx.x >> 5;
    int c0 = tx * 4;
    float acc[4][4] = {};
    for (int i = 0; i < FDIM; ++i) {
        float4 w = *(const float4*)&sWs[i * FDIM + c0];
        float f0 = sF[ty * 4 + 0][i];
        float f1 = sF[ty * 4 + 1][i];
        float f2 = sF[ty * 4 + 2][i];
        float f3 = sF[ty * 4 + 3][i];
        acc[0][0] = fmaf(f0, w.x, acc[0][0]); acc[0][1] = fmaf(f0, w.y, acc[0][1]);
        acc[0][2] = fmaf(f0, w.z, acc[0][2]); acc[0][3] = fmaf(f0, w.w, acc[0][3]);
        acc[1][0] = fmaf(f1, w.x, acc[1][0]); acc[1][1] = fmaf(f1, w.y, acc[1][1]);
        acc[1][2] = fmaf(f1, w.z, acc[1][2]); acc[1][3] = fmaf(f1, w.w, acc[1][3]);
        acc[2][0] = fmaf(f2, w.x, acc[2][0]); acc[2][1] = fmaf(f2, w.y, acc[2][1]);
        acc[2][2] = fmaf(f2, w.z, acc[2][2]); acc[2][3] = fmaf(f2, w.w, acc[2][3]);
        acc[3][0] = fmaf(f3, w.x, acc[3][0]); acc[3][1] = fmaf(f3, w.y, acc[3][1]);
        acc[3][2] = fmaf(f3, w.z, acc[3][2]); acc[3][3] = fmaf(f3, w.w, acc[3][3]);
    }
    for (int r = 0; r < 4; ++r) {
        int gr = row0 + ty * 4 + r;
        if (gr < N) {
            ushort4 o;
            o.x = f2bf(acc[r][0]); o.y = f2bf(acc[r][1]);
            o.z = f2bf(acc[r][2]); o.w = f2bf(acc[r][3]);
            *(ushort4*)(Gbf + (size_t)gr * FDIM + c0) = o;
        }
    }
}

// ---- k2: per-bucket totals, tot[b] = sum_k M[k][b] (x8 unrolled, coalesced) ----
__global__ __launch_bounds__(256) void k_btot(const unsigned* __restrict__ M, int nb,
                                              unsigned* __restrict__ tot) {
    int b = blockIdx.x * 256 + threadIdx.x;
    if (b < nb) {
        unsigned s = 0;
        for (int k = 0; k < NBLK; k += 8) {
            unsigned t0 = M[(size_t)(k + 0) * nb + b];
            unsigned t1 = M[(size_t)(k + 1) * nb + b];
            unsigned t2 = M[(size_t)(k + 2) * nb + b];
            unsigned t3 = M[(size_t)(k + 3) * nb + b];
            unsigned t4 = M[(size_t)(k + 4) * nb + b];
            unsigned t5 = M[(size_t)(k + 5) * nb + b];
            unsigned t6 = M[(size_t)(k + 6) * nb + b];
            unsigned t7 = M[(size_t)(k + 7) * nb + b];
            s += t0 + t1 + t2 + t3 + t4 + t5 + t6 + t7;
        }
        tot[b] = s;
    }
}

// ---- k3: single-block exclusive scan of tot -> bucketStart (8/thread) ----
__global__ __launch_bounds__(256) void k_bscan(const unsigned* __restrict__ tot, int nb,
                                               unsigned* __restrict__ bucketStart) {
    __shared__ unsigned wS[4];
    int t = threadIdx.x;
    unsigned v0, v1, v2, v3, v4, v5, v6, v7;
    int b0 = t * 8;
    v0 = (b0 + 0 < nb) ? tot[b0 + 0] : 0u;
    v1 = (b0 + 1 < nb) ? tot[b0 + 1] : 0u;
    v2 = (b0 + 2 < nb) ? tot[b0 + 2] : 0u;
    v3 = (b0 + 3 < nb) ? tot[b0 + 3] : 0u;
    v4 = (b0 + 4 < nb) ? tot[b0 + 4] : 0u;
    v5 = (b0 + 5 < nb) ? tot[b0 + 5] : 0u;
    v6 = (b0 + 6 < nb) ? tot[b0 + 6] : 0u;
    v7 = (b0 + 7 < nb) ? tot[b0 + 7] : 0u;
    unsigned l0 = 0, l1 = v0, l2 = l1 + v1, l3 = l2 + v2, l4 = l3 + v3,
             l5 = l4 + v4, l6 = l5 + v5, l7 = l6 + v6;
    unsigned s = l7 + v7;
    int lane = t & 63, wid = t >> 6;
    unsigned incl = s;
    for (int d = 1; d < 64; d <<= 1) {
        unsigned u = __shfl_up(incl, d, 64);
        if (lane >= d) incl += u;
    }
    if (lane == 63) wS[wid] = incl;
    __syncthreads();
    unsigned wOff = 0;
    for (int i = 0; i < wid; ++i) wOff += wS[i];
    unsigned base = wOff + incl - s;
    if (b0 + 0 < nb) bucketStart[b0 + 0] = base + l0;
    if (b0 + 1 < nb) bucketStart[b0 + 1] = base + l1;
    if (b0 + 2 < nb) bucketStart[b0 + 2] = base + l2;
    if (b0 + 3 < nb) bucketStart[b0 + 3] = base + l3;
    if (b0 + 4 < nb) bucketStart[b0 + 4] = base + l4;
    if (b0 + 5 < nb) bucketStart[b0 + 5] = base + l5;
    if (b0 + 6 < nb) bucketStart[b0 + 6] = base + l6;
    if (b0 + 7 < nb) bucketStart[b0 + 7] = base + l7;
    if (t == 255) bucketStart[nb] = base + s;
}

// ---- k4: per-bucket running prefix over k: M[k][b] -> cursor starts ----
__global__ __launch_bounds__(256) void k_mscan(unsigned* __restrict__ M, int nb,
                                               const unsigned* __restrict__ bucketStart) {
    int b = blockIdx.x * 256 + threadIdx.x;
    if (b < nb) {
        unsigned run = bucketStart[b];
        for (int k = 0; k < NBLK; k += 8) {
            unsigned t0 = M[(size_t)(k + 0) * nb + b];
            unsigned t1 = M[(size_t)(k + 1) * nb + b];
            unsigned t2 = M[(size_t)(k + 2) * nb + b];
            unsigned t3 = M[(size_t)(k + 3) * nb + b];
            unsigned t4 = M[(size_t)(k + 4) * nb + b];
            unsigned t5 = M[(size_t)(k + 5) * nb + b];
            unsigned t6 = M[(size_t)(k + 6) * nb + b];
            unsigned t7 = M[(size_t)(k + 7) * nb + b];
            M[(size_t)(k + 0) * nb + b] = run; run += t0;
            M[(size_t)(k + 1) * nb + b] = run; run += t1;
            M[(size_t)(k + 2) * nb + b] = run; run += t2;
            M[(size_t)(k + 3) * nb + b] = run; run += t3;
            M[(size_t)(k + 4) * nb + b] = run; run += t4;
            M[(size_t)(k + 5) * nb + b] = run; run += t5;
            M[(size_t)(k + 6) * nb + b] = run; run += t6;
            M[(size_t)(k + 7) * nb + b] = run; run += t7;
        }
    }
}

// ---- k5: scatter via LDS cursors. 64 blocks x 1024 thr, chunk=25K ->
// per-(bucket,block) runs avg 16 entries = one 64B line (no cross-XCD bounce). ----
__global__ __launch_bounds__(1024) void k_scatter(const int* __restrict__ idx,
                                                  const int* __restrict__ mol, int E,
                                                  int nb, const unsigned* __restrict__ M,
                                                  unsigned* __restrict__ sortedE) {
    extern __shared__ unsigned cur[];
    int bid = blockIdx.x;
    for (int i = threadIdx.x; i < nb; i += 1024)
        cur[i] = M[(size_t)bid * nb + i];
    __syncthreads();
    int chunk = (E + NBLK - 1) / NBLK;
    int s = bid * chunk;
    int e_end = min(E, s + chunk);
    for (int e = s + threadIdx.x; e < e_end; e += 1024) {
        int i0 = idx[e];
        int i1 = idx[E + e];
        int m  = mol[e];
        int b  = i1 >> 5;
        int loc = i1 & 31;
        unsigned pos = atomicAdd(&cur[b], 1u);
        sortedE[pos] = (unsigned)i0 | ((unsigned)m << 16) | ((unsigned)loc << 26);
    }
}

// ---- k6: edge kernel (R6 exact). One WG per bucket: F window (fp32->bf16) in
// LDS, gather G, accumulate per-molecule in LDS smol, flush plain stores. ----
__global__ __launch_bounds__(256) void edge_kernel(
    const unsigned short* __restrict__ Gbf, const float* __restrict__ Fm,
    const unsigned* __restrict__ sortedE, const unsigned* __restrict__ bucketStart,
    float* __restrict__ part, int N, int Mout) {
    __shared__ unsigned short sFrow[BROWS * FDIM];   // 8 KB
    __shared__ float smol[1024];                     // 4 KB

    int b = blockIdx.x;
    int row0 = b * BROWS;
    int nrow = min(BROWS, N - row0);
    for (int k = threadIdx.x; k < nrow * (FDIM / 4); k += 256) {
        int r = k >> 5, c = k & 31;
        float4 v = ((const float4*)(Fm + (size_t)(row0 + r) * FDIM))[c];
        ushort4 o;
        o.x = f2bf(v.x); o.y = f2bf(v.y); o.z = f2bf(v.z); o.w = f2bf(v.w);
        *(ushort4*)(sFrow + r * FDIM + c * 4) = o;
    }
    for (int i = threadIdx.x; i < 1024; i += 256) smol[i] = 0.f;
    __syncthreads();

    const int s = bucketStart[b];
    const int e_end = bucketStart[b + 1];
    const int lane = threadIdx.x & 63;
    const int sub  = lane >> 4;
    const int t16  = lane & 15;
    const int off16 = t16 * 8;
    const int wid  = threadIdx.x >> 6;

    for (int base = s + wid * 4; base < e_end; base += 16) {
        int e = base + sub;
        bool valid = (e < e_end);
        unsigned pk = valid ? sortedE[e] : 0u;
        int i0  = pk & 0xffff;
        int m   = (pk >> 16) & 0x3ff;
        int loc = pk >> 26;
        const uint4 g = *(const uint4*)(Gbf + (size_t)i0 * FDIM + off16);
        const uint4 f = *(const uint4*)(sFrow + loc * FDIM + off16);
        float p;
        p = bf_lo(g.x) * bf_lo(f.x);
        p = fmaf(bf_hi(g.x), bf_hi(f.x), p);
        p = fmaf(bf_lo(g.y), bf_lo(f.y), p);
        p = fmaf(bf_hi(g.y), bf_hi(f.y), p);
        p = fmaf(bf_lo(g.z), bf_lo(f.z), p);
        p = fmaf(bf_hi(g.z), bf_hi(f.z), p);
        p = fmaf(bf_lo(g.w), bf_lo(f.w), p);
        p = fmaf(bf_hi(g.w), bf_hi(f.w), p);
        p += __shfl_xor(p, 1, 16);
        p += __shfl_xor(p, 2, 16);
        p += __shfl_xor(p, 4, 16);
        p += __shfl_xor(p, 8, 16);
        if (t16 == 0 && valid) atomicAdd(&smol[m], p);
    }
    __syncthreads();
    float* prow = part + (size_t)b * 1024;
    for (int i = threadIdx.x; i < 1024; i += 256) prow[i] = smol[i];
}

// ---- k7: single-dispatch reduction: 16 blocks, block bb owns 64 outputs ----
__global__ __launch_bounds__(256) void k_red(const float* __restrict__ part, int nb,
                                             float* __restrict__ out, int Mout) {
    __shared__ float red[256];
    int bb = blockIdx.x, t = threadIdx.x;
    int m = bb * 64 + (t & 63);
    int sl = t >> 6;          // 0..3
    float s = 0.f;
    for (int b = sl; b < nb; b += 4)
        s += part[(size_t)b * 1024 + m];
    red[t] = s;
    __syncthreads();
    if (t < 64 && m < Mout)
        out[m] = red[t] + red[t + 64] + red[t + 128] + red[t + 192];
}

extern "C" void kernel_launch(void* const* d_in, const int* in_sizes, int n_in,
                              void* d_out, int out_size, void* d_ws, size_t ws_size,
                              hipStream_t stream) {
    const float* Fm = (const float*)d_in[0];
    const float* W  = (const float*)d_in[1];
    const int* idx  = (const int*)d_in[2];
    const int* mol  = (const int*)d_in[3];
    float* out = (float*)d_out;

    const int N = in_sizes[0] / FDIM;   // 50000
    const int E = in_sizes[3];          // 1600000
    const int nb = (N + BROWS - 1) / BROWS;   // 1563
    const int gemmBlocks = (N + 31) / 32;     // 1563

    // workspace layout (~26 MB)
    char* ws = (char*)d_ws;
    size_t o = 0;
    unsigned short* Gbf = (unsigned short*)(ws + o); o += ((size_t)N * FDIM * 2 + 255) & ~(size_t)255;
    unsigned* sortedE = (unsigned*)(ws + o);         o += ((size_t)E * 4 + 255) & ~(size_t)255;
    unsigned* M = (unsigned*)(ws + o);               o += ((size_t)NBLK * nb * 4 + 255) & ~(size_t)255;
    unsigned* tot = (unsigned*)(ws + o);             o += ((size_t)nb * 4 + 255) & ~(size_t)255;
    unsigned* bucketStart = (unsigned*)(ws + o);     o += ((size_t)(nb + 1) * 4 + 255) & ~(size_t)255;
    float* part = (float*)(ws + o);                  o += (size_t)nb * 1024 * sizeof(float);

    k_gemm_hist<<<gemmBlocks + NBLK, 256, 0, stream>>>(
        Fm, W, idx, Gbf, M, N, E, nb, gemmBlocks);
    k_btot<<<(nb + 255) / 256, 256, 0, stream>>>(M, nb, tot);
    k_bscan<<<1, 256, 0, stream>>>(tot, nb, bucketStart);
    k_mscan<<<(nb + 255) / 256, 256, 0, stream>>>(M, nb, bucketStart);
    k_scatter<<<NBLK, 1024, (size_t)nb * 4, stream>>>(idx, mol, E, nb, M, sortedE);
    edge_kernel<<<nb, 256, 0, stream>>>(Gbf, Fm, sortedE, bucketStart, part, N, out_size);
    k_red<<<16, 256, 0, stream>>>(part, nb, out, out_size);
}

// Round 10
// 311.228 us; speedup vs baseline: 1.9226x; 1.2607x over previous
//
#include <hip/hip_runtime.h>
#include <hip/hip_bf16.h>

#define FDIM 128
#define BROWS 32     // i1 rows per bucket: bin = i1>>5, loc = i1&31
#define NBLK 128     // hist/scatter partitions: runs of ~8 = 32B per line per block

// ---- bf16 helpers (manual, RNE) ----
static __device__ __forceinline__ unsigned short f2bf(float x) {
    unsigned u = __float_as_uint(x);
    unsigned r = 0x7fffu + ((u >> 16) & 1u);
    return (unsigned short)((u + r) >> 16);
}
static __device__ __forceinline__ float bf_lo(unsigned u) { return __uint_as_float(u << 16); }
static __device__ __forceinline__ float bf_hi(unsigned u) { return __uint_as_float(u & 0xffff0000u); }

// ---- k1: gemm + fused histogram.
// Blocks [0,gemmBlocks): G = F @ (W+W^T) bf16. W loaded coalesced; W^T added
// via in-LDS pairwise transpose-add (each (i,j)/(j,i) pair owned by 1 thread).
// Blocks [gemmBlocks, gemmBlocks+NBLK): LDS histogram -> M[k][b].
__global__ __launch_bounds__(256, 2) void k_gemm_hist(
    const float* __restrict__ Fm, const float* __restrict__ W,
    const int* __restrict__ idx, unsigned short* __restrict__ Gbf,
    unsigned* __restrict__ M, int N, int E, int nb, int gemmBlocks) {
    __shared__ float sWs[FDIM * FDIM];   // 64 KB (hist blocks reuse as counters)
    __shared__ float sF[32][FDIM];       // 16 KB

    int bid = blockIdx.x;
    if (bid >= gemmBlocks) {
        // ---- hist path ----
        int hb = bid - gemmBlocks;
        unsigned* cnt = (unsigned*)sWs;
        for (int i = threadIdx.x; i < nb; i += 256) cnt[i] = 0;
        __syncthreads();
        int chunk = (E + NBLK - 1) / NBLK;
        int s = hb * chunk;
        int e_end = min(E, s + chunk);
        for (int e = s + threadIdx.x; e < e_end; e += 256) {
            int i1 = idx[E + e];
            atomicAdd(&cnt[i1 >> 5], 1u);
        }
        __syncthreads();
        for (int i = threadIdx.x; i < nb; i += 256)
            M[(size_t)hb * nb + i] = cnt[i];
        return;
    }

    // ---- gemm path ----
    for (int k = threadIdx.x; k < 4096; k += 256)
        ((float4*)sWs)[k] = ((const float4*)W)[k];
    int row0 = bid * 32;
    for (int k = threadIdx.x; k < 32 * FDIM / 4; k += 256) {
        int r = k >> 5, c = k & 31;
        int gr = row0 + r;
        float4 v = make_float4(0.f, 0.f, 0.f, 0.f);
        if (gr < N) v = ((const float4*)Fm)[(size_t)gr * (FDIM / 4) + c];
        ((float4*)&sF[r][0])[c] = v;
    }
    __syncthreads();
    // in-LDS symmetrize: sWs = W + W^T
    for (int k = threadIdx.x; k < FDIM * FDIM; k += 256) {
        int i = k >> 7, j = k & 127;
        if (i < j) {
            float a = sWs[i * FDIM + j];
            float c = sWs[j * FDIM + i];
            float sum = a + c;
            sWs[i * FDIM + j] = sum;
            sWs[j * FDIM + i] = sum;
        } else if (i == j) {
            sWs[i * FDIM + i] *= 2.0f;
        }
    }
    __syncthreads();

    int tx = threadIdx.x & 31;
    int ty = threadIdx.x >> 5;
    int c0 = tx * 4;
    float acc[4][4] = {};
    for (int i = 0; i < FDIM; ++i) {
        float4 w = *(const float4*)&sWs[i * FDIM + c0];
        float f0 = sF[ty * 4 + 0][i];
        float f1 = sF[ty * 4 + 1][i];
        float f2 = sF[ty * 4 + 2][i];
        float f3 = sF[ty * 4 + 3][i];
        acc[0][0] = fmaf(f0, w.x, acc[0][0]); acc[0][1] = fmaf(f0, w.y, acc[0][1]);
        acc[0][2] = fmaf(f0, w.z, acc[0][2]); acc[0][3] = fmaf(f0, w.w, acc[0][3]);
        acc[1][0] = fmaf(f1, w.x, acc[1][0]); acc[1][1] = fmaf(f1, w.y, acc[1][1]);
        acc[1][2] = fmaf(f1, w.z, acc[1][2]); acc[1][3] = fmaf(f1, w.w, acc[1][3]);
        acc[2][0] = fmaf(f2, w.x, acc[2][0]); acc[2][1] = fmaf(f2, w.y, acc[2][1]);
        acc[2][2] = fmaf(f2, w.z, acc[2][2]); acc[2][3] = fmaf(f2, w.w, acc[2][3]);
        acc[3][0] = fmaf(f3, w.x, acc[3][0]); acc[3][1] = fmaf(f3, w.y, acc[3][1]);
        acc[3][2] = fmaf(f3, w.z, acc[3][2]); acc[3][3] = fmaf(f3, w.w, acc[3][3]);
    }
    for (int r = 0; r < 4; ++r) {
        int gr = row0 + ty * 4 + r;
        if (gr < N) {
            ushort4 o;
            o.x = f2bf(acc[r][0]); o.y = f2bf(acc[r][1]);
            o.z = f2bf(acc[r][2]); o.w = f2bf(acc[r][3]);
            *(ushort4*)(Gbf + (size_t)gr * FDIM + c0) = o;
        }
    }
}

// ---- k2: per-bucket totals, tot[b] = sum_k M[k][b] (x8 unrolled, coalesced) ----
__global__ __launch_bounds__(256) void k_btot(const unsigned* __restrict__ M, int nb,
                                              unsigned* __restrict__ tot) {
    int b = blockIdx.x * 256 + threadIdx.x;
    if (b < nb) {
        unsigned s = 0;
        for (int k = 0; k < NBLK; k += 8) {
            unsigned t0 = M[(size_t)(k + 0) * nb + b];
            unsigned t1 = M[(size_t)(k + 1) * nb + b];
            unsigned t2 = M[(size_t)(k + 2) * nb + b];
            unsigned t3 = M[(size_t)(k + 3) * nb + b];
            unsigned t4 = M[(size_t)(k + 4) * nb + b];
            unsigned t5 = M[(size_t)(k + 5) * nb + b];
            unsigned t6 = M[(size_t)(k + 6) * nb + b];
            unsigned t7 = M[(size_t)(k + 7) * nb + b];
            s += t0 + t1 + t2 + t3 + t4 + t5 + t6 + t7;
        }
        tot[b] = s;
    }
}

// ---- k3: single-block exclusive scan of tot -> bucketStart (8/thread) ----
__global__ __launch_bounds__(256) void k_bscan(const unsigned* __restrict__ tot, int nb,
                                               unsigned* __restrict__ bucketStart) {
    __shared__ unsigned wS[4];
    int t = threadIdx.x;
    unsigned v0, v1, v2, v3, v4, v5, v6, v7;
    int b0 = t * 8;
    v0 = (b0 + 0 < nb) ? tot[b0 + 0] : 0u;
    v1 = (b0 + 1 < nb) ? tot[b0 + 1] : 0u;
    v2 = (b0 + 2 < nb) ? tot[b0 + 2] : 0u;
    v3 = (b0 + 3 < nb) ? tot[b0 + 3] : 0u;
    v4 = (b0 + 4 < nb) ? tot[b0 + 4] : 0u;
    v5 = (b0 + 5 < nb) ? tot[b0 + 5] : 0u;
    v6 = (b0 + 6 < nb) ? tot[b0 + 6] : 0u;
    v7 = (b0 + 7 < nb) ? tot[b0 + 7] : 0u;
    unsigned l0 = 0, l1 = v0, l2 = l1 + v1, l3 = l2 + v2, l4 = l3 + v3,
             l5 = l4 + v4, l6 = l5 + v5, l7 = l6 + v6;
    unsigned s = l7 + v7;
    int lane = t & 63, wid = t >> 6;
    unsigned incl = s;
    for (int d = 1; d < 64; d <<= 1) {
        unsigned u = __shfl_up(incl, d, 64);
        if (lane >= d) incl += u;
    }
    if (lane == 63) wS[wid] = incl;
    __syncthreads();
    unsigned wOff = 0;
    for (int i = 0; i < wid; ++i) wOff += wS[i];
    unsigned base = wOff + incl - s;
    if (b0 + 0 < nb) bucketStart[b0 + 0] = base + l0;
    if (b0 + 1 < nb) bucketStart[b0 + 1] = base + l1;
    if (b0 + 2 < nb) bucketStart[b0 + 2] = base + l2;
    if (b0 + 3 < nb) bucketStart[b0 + 3] = base + l3;
    if (b0 + 4 < nb) bucketStart[b0 + 4] = base + l4;
    if (b0 + 5 < nb) bucketStart[b0 + 5] = base + l5;
    if (b0 + 6 < nb) bucketStart[b0 + 6] = base + l6;
    if (b0 + 7 < nb) bucketStart[b0 + 7] = base + l7;
    if (t == 255) bucketStart[nb] = base + s;
}

// ---- k4: per-bucket running prefix over k: M[k][b] -> cursor starts ----
__global__ __launch_bounds__(256) void k_mscan(unsigned* __restrict__ M, int nb,
                                               const unsigned* __restrict__ bucketStart) {
    int b = blockIdx.x * 256 + threadIdx.x;
    if (b < nb) {
        unsigned run = bucketStart[b];
        for (int k = 0; k < NBLK; k += 8) {
            unsigned t0 = M[(size_t)(k + 0) * nb + b];
            unsigned t1 = M[(size_t)(k + 1) * nb + b];
            unsigned t2 = M[(size_t)(k + 2) * nb + b];
            unsigned t3 = M[(size_t)(k + 3) * nb + b];
            unsigned t4 = M[(size_t)(k + 4) * nb + b];
            unsigned t5 = M[(size_t)(k + 5) * nb + b];
            unsigned t6 = M[(size_t)(k + 6) * nb + b];
            unsigned t7 = M[(size_t)(k + 7) * nb + b];
            M[(size_t)(k + 0) * nb + b] = run; run += t0;
            M[(size_t)(k + 1) * nb + b] = run; run += t1;
            M[(size_t)(k + 2) * nb + b] = run; run += t2;
            M[(size_t)(k + 3) * nb + b] = run; run += t3;
            M[(size_t)(k + 4) * nb + b] = run; run += t4;
            M[(size_t)(k + 5) * nb + b] = run; run += t5;
            M[(size_t)(k + 6) * nb + b] = run; run += t6;
            M[(size_t)(k + 7) * nb + b] = run; run += t7;
        }
    }
}

// ---- k5: scatter via LDS cursors. 128 blocks x 512 thr, chunk=12.5K ->
// per-(bucket,block) runs avg 8 entries (32B), <=2 partitions per line. ----
__global__ __launch_bounds__(512) void k_scatter(const int* __restrict__ idx,
                                                 const int* __restrict__ mol, int E,
                                                 int nb, const unsigned* __restrict__ M,
                                                 unsigned* __restrict__ sortedE) {
    extern __shared__ unsigned cur[];
    int bid = blockIdx.x;
    for (int i = threadIdx.x; i < nb; i += 512)
        cur[i] = M[(size_t)bid * nb + i];
    __syncthreads();
    int chunk = (E + NBLK - 1) / NBLK;
    int s = bid * chunk;
    int e_end = min(E, s + chunk);
    for (int e = s + threadIdx.x; e < e_end; e += 512) {
        int i0 = idx[e];
        int i1 = idx[E + e];
        int m  = mol[e];
        int b  = i1 >> 5;
        int loc = i1 & 31;
        unsigned pos = atomicAdd(&cur[b], 1u);
        sortedE[pos] = (unsigned)i0 | ((unsigned)m << 16) | ((unsigned)loc << 26);
    }
}

// ---- k6: edge kernel (R6 exact, 69us known-good). One WG per bucket. ----
__global__ __launch_bounds__(256) void edge_kernel(
    const unsigned short* __restrict__ Gbf, const float* __restrict__ Fm,
    const unsigned* __restrict__ sortedE, const unsigned* __restrict__ bucketStart,
    float* __restrict__ part, int N, int Mout) {
    __shared__ unsigned short sFrow[BROWS * FDIM];   // 8 KB
    __shared__ float smol[1024];                     // 4 KB

    int b = blockIdx.x;
    int row0 = b * BROWS;
    int nrow = min(BROWS, N - row0);
    for (int k = threadIdx.x; k < nrow * (FDIM / 4); k += 256) {
        int r = k >> 5, c = k & 31;
        float4 v = ((const float4*)(Fm + (size_t)(row0 + r) * FDIM))[c];
        ushort4 o;
        o.x = f2bf(v.x); o.y = f2bf(v.y); o.z = f2bf(v.z); o.w = f2bf(v.w);
        *(ushort4*)(sFrow + r * FDIM + c * 4) = o;
    }
    for (int i = threadIdx.x; i < 1024; i += 256) smol[i] = 0.f;
    __syncthreads();

    const int s = bucketStart[b];
    const int e_end = bucketStart[b + 1];
    const int lane = threadIdx.x & 63;
    const int sub  = lane >> 4;
    const int t16  = lane & 15;
    const int off16 = t16 * 8;
    const int wid  = threadIdx.x >> 6;

    for (int base = s + wid * 4; base < e_end; base += 16) {
        int e = base + sub;
        bool valid = (e < e_end);
        unsigned pk = valid ? sortedE[e] : 0u;
        int i0  = pk & 0xffff;
        int m   = (pk >> 16) & 0x3ff;
        int loc = pk >> 26;
        const uint4 g = *(const uint4*)(Gbf + (size_t)i0 * FDIM + off16);
        const uint4 f = *(const uint4*)(sFrow + loc * FDIM + off16);
        float p;
        p = bf_lo(g.x) * bf_lo(f.x);
        p = fmaf(bf_hi(g.x), bf_hi(f.x), p);
        p = fmaf(bf_lo(g.y), bf_lo(f.y), p);
        p = fmaf(bf_hi(g.y), bf_hi(f.y), p);
        p = fmaf(bf_lo(g.z), bf_lo(f.z), p);
        p = fmaf(bf_hi(g.z), bf_hi(f.z), p);
        p = fmaf(bf_lo(g.w), bf_lo(f.w), p);
        p = fmaf(bf_hi(g.w), bf_hi(f.w), p);
        p += __shfl_xor(p, 1, 16);
        p += __shfl_xor(p, 2, 16);
        p += __shfl_xor(p, 4, 16);
        p += __shfl_xor(p, 8, 16);
        if (t16 == 0 && valid) atomicAdd(&smol[m], p);
    }
    __syncthreads();
    float* prow = part + (size_t)b * 1024;
    for (int i = threadIdx.x; i < 1024; i += 256) prow[i] = smol[i];
}

// ---- k7: reduction, 128 blocks (32 slices x 4 col-chunks), coalesced reads,
// 256 atomicAdds per block into pre-zeroed out (32K atomics ~ 2-3us). ----
__global__ __launch_bounds__(256) void k_red(const float* __restrict__ part, int nb,
                                             float* __restrict__ out, int Mout) {
    int slice = blockIdx.x >> 2;          // 0..31
    int chunk = blockIdx.x & 3;           // 0..3
    int col = chunk * 256 + threadIdx.x;  // 0..1023
    float s = 0.f;
    for (int b = slice; b < nb; b += 32)
        s += part[(size_t)b * 1024 + col];
    if (col < Mout) atomicAdd(&out[col], s);
}

extern "C" void kernel_launch(void* const* d_in, const int* in_sizes, int n_in,
                              void* d_out, int out_size, void* d_ws, size_t ws_size,
                              hipStream_t stream) {
    const float* Fm = (const float*)d_in[0];
    const float* W  = (const float*)d_in[1];
    const int* idx  = (const int*)d_in[2];
    const int* mol  = (const int*)d_in[3];
    float* out = (float*)d_out;

    const int N = in_sizes[0] / FDIM;   // 50000
    const int E = in_sizes[3];          // 1600000
    const int nb = (N + BROWS - 1) / BROWS;   // 1563
    const int gemmBlocks = (N + 31) / 32;     // 1563

    // workspace layout (~27 MB)
    char* ws = (char*)d_ws;
    size_t o = 0;
    unsigned short* Gbf = (unsigned short*)(ws + o); o += ((size_t)N * FDIM * 2 + 255) & ~(size_t)255;
    unsigned* sortedE = (unsigned*)(ws + o);         o += ((size_t)E * 4 + 255) & ~(size_t)255;
    unsigned* M = (unsigned*)(ws + o);               o += ((size_t)NBLK * nb * 4 + 255) & ~(size_t)255;
    unsigned* tot = (unsigned*)(ws + o);             o += ((size_t)nb * 4 + 255) & ~(size_t)255;
    unsigned* bucketStart = (unsigned*)(ws + o);     o += ((size_t)(nb + 1) * 4 + 255) & ~(size_t)255;
    float* part = (float*)(ws + o);                  o += (size_t)nb * 1024 * sizeof(float);

    hipMemsetAsync(out, 0, (size_t)out_size * sizeof(float), stream);

    k_gemm_hist<<<gemmBlocks + NBLK, 256, 0, stream>>>(
        Fm, W, idx, Gbf, M, N, E, nb, gemmBlocks);
    k_btot<<<(nb + 255) / 256, 256, 0, stream>>>(M, nb, tot);
    k_bscan<<<1, 256, 0, stream>>>(tot, nb, bucketStart);
    k_mscan<<<(nb + 255) / 256, 256, 0, stream>>>(M, nb, bucketStart);
    k_scatter<<<NBLK, 512, (size_t)nb * 4, stream>>>(idx, mol, E, nb, M, sortedE);
    edge_kernel<<<nb, 256, 0, stream>>>(Gbf, Fm, sortedE, bucketStart, part, N, out_size);
    k_red<<<128, 256, 0, stream>>>(part, nb, out, out_size);
}